// Round 3
// baseline (580.685 us; speedup 1.0000x reference)
//
#include <hip/hip_runtime.h>
#include <hip/hip_bf16.h>

typedef __bf16 bf16;
typedef __bf16 bf16x8 __attribute__((ext_vector_type(8)));
typedef __bf16 bf16x4 __attribute__((ext_vector_type(4)));
typedef float f32x4 __attribute__((ext_vector_type(4)));
typedef unsigned int u32;
typedef unsigned short u16;

constexpr int B_ = 4, S = 2048, D = 1024, H = 16, HD = 64;
constexpr int M = B_ * S;  // 8192

#define MFMA(a, b, c) __builtin_amdgcn_mfma_f32_16x16x32_bf16(a, b, c, 0, 0, 0)

// ---- async global->LDS, 16 B per lane (dest = wave-uniform base + lane*16) ----
__device__ inline void gl_lds16(const bf16* g, bf16* l) {
  __builtin_amdgcn_global_load_lds(
      (const __attribute__((address_space(1))) u32*)g,
      (__attribute__((address_space(3))) u32*)l, 16, 0, 0);
}

__device__ inline bf16x8 load8(const void* base, size_t idx, bool isf32) {
  if (isf32) {
    const float* p = (const float*)base + idx;
    const float4 a = *(const float4*)p;
    const float4 b = *(const float4*)(p + 4);
    bf16x8 r;
    r[0] = (bf16)a.x; r[1] = (bf16)a.y; r[2] = (bf16)a.z; r[3] = (bf16)a.w;
    r[4] = (bf16)b.x; r[5] = (bf16)b.y; r[6] = (bf16)b.z; r[7] = (bf16)b.w;
    return r;
  }
  return *(const bf16x8*)((const bf16*)base + idx);
}
__device__ inline float load1(const void* base, size_t idx, bool isf32) {
  return isf32 ? ((const float*)base)[idx] : (float)((const bf16*)base)[idx];
}
// 4 consecutive mask values (idx multiple of 4 -> aligned)
__device__ inline f32x4 load4(const void* base, size_t idx, bool isf32) {
  if (isf32) {
    const float4 v = *(const float4*)((const float*)base + idx);
    return {v.x, v.y, v.z, v.w};
  }
  const bf16x4 v = *(const bf16x4*)((const bf16*)base + idx);
  return {(float)v[0], (float)v[1], (float)v[2], (float)v[3]};
}

// ---------------------------------------------------------------------------
// flag bit0 = inputs are fp32; bit1 = mask has a nonzero element.
// flag is zeroed via hipMemsetAsync before these run.
// ---------------------------------------------------------------------------
__global__ __launch_bounds__(256) void detect_dtype(const uint4* __restrict__ X,
                                                    int* __restrict__ flag) {
  bool hit = false;
  for (int i = blockIdx.x * 256 + threadIdx.x; i < 32768; i += 64 * 256) {
    const uint4 v = X[i];
    const u32 w[4] = {v.x, v.y, v.z, v.w};
#pragma unroll
    for (int j = 0; j < 4; j++) {
      if (((w[j] >> 7) & 0xFFu) == 0xFFu) hit = true;
      if (((w[j] >> 23) & 0xFFu) == 0xFFu) hit = true;
    }
  }
  __shared__ int s;
  if (threadIdx.x == 0) s = 0;
  __syncthreads();
  if (hit) atomicOr(&s, 1);
  __syncthreads();
  if (threadIdx.x == 0 && s) atomicOr(flag, 1);
}

// runs after detect_dtype (stream-ordered): reads bit0 to size the mask scan.
__global__ __launch_bounds__(256) void detect_mask(const uint4* __restrict__ Mk,
                                                   int* __restrict__ flag) {
  const bool isf32 = (*flag & 1) != 0;
  const int n4 = (B_ * S * (isf32 ? 4 : 2)) / 16;  // 2048 (f32) or 1024 (bf16)
  bool nz = false;
  for (int i = blockIdx.x * 256 + threadIdx.x; i < n4; i += 8 * 256) {
    const uint4 v = Mk[i];
    nz |= ((v.x | v.y | v.z | v.w) != 0u);
  }
  __shared__ int s;
  if (threadIdx.x == 0) s = 0;
  __syncthreads();
  if (nz) atomicOr(&s, 1);
  __syncthreads();
  if (threadIdx.x == 0 && s) atomicOr(flag, 2);
}

// ---------------------------------------------------------------------------
// fp32 only: convert X -> Xb (d_out[0,16MB)), W q/k/v -> Wb (d_out+16MB).
// ---------------------------------------------------------------------------
__global__ __launch_bounds__(256) void convert_inputs(
    const void* __restrict__ X, const void* __restrict__ W0,
    const void* __restrict__ W1, const void* __restrict__ W2,
    bf16* __restrict__ Xb, bf16* __restrict__ Wb,
    const int* __restrict__ flagp) {
  if ((*flagp & 1) == 0) return;
  const int seg = blockIdx.y;
  const size_t n = (seg == 0) ? (size_t)M * D : (size_t)D * D;
  const size_t i0 = ((size_t)blockIdx.x * 256 + threadIdx.x) * 8;
  if (i0 >= n) return;
  const void* src = seg == 0 ? X : seg == 1 ? W0 : seg == 2 ? W1 : W2;
  bf16* dst = seg == 0 ? Xb : Wb + (size_t)(seg - 1) * D * D;
  *(bf16x8*)(dst + i0) = load8(src, i0, true);
}

// ---------------------------------------------------------------------------
// QKV GEMM, grid.z = {Q,K,V}. Async-staged bf16 A and B (m97 path).
// z==0: Q*(0.125*log2e) [B,H,S,HD]; z==1: K; z==2: Vt [B,H,HD,S].
// ---------------------------------------------------------------------------
__global__ __launch_bounds__(256) void qkv_gemm(
    const void* __restrict__ X0, const bf16* __restrict__ Xb,
    const void* __restrict__ W0, const void* __restrict__ W1, const void* __restrict__ W2,
    const void* __restrict__ b0, const void* __restrict__ b1, const void* __restrict__ b2,
    bf16* __restrict__ Qo, bf16* __restrict__ Ko, bf16* __restrict__ Vo,
    const bf16* __restrict__ Wb, const int* __restrict__ flagp) {
  const int z = blockIdx.z;
  const bool isf32 = (*flagp & 1) != 0;
  const void* Worig = z == 0 ? W0 : z == 1 ? W1 : W2;
  const void* bias  = z == 0 ? b0 : z == 1 ? b1 : b2;
  bf16* out         = z == 0 ? Qo : z == 1 ? Ko : Vo;
  const bf16* Xs = isf32 ? Xb : (const bf16*)X0;
  const bf16* Ws = isf32 ? (Wb + (size_t)z * D * D) : (const bf16*)Worig;

  __shared__ __align__(16) bf16 As[128 * 32];
  __shared__ __align__(16) bf16 Bs[128 * 32];
  const int tid = threadIdx.x, lane = tid & 63, wave = tid >> 6;
  const int q16 = lane & 15, quad = lane >> 4;
  const int wm = (wave & 1) * 64, wn = (wave >> 1) * 64;
  const int bm = blockIdx.x * 128, bn = blockIdx.y * 128;
  const int r0 = tid >> 2, kg = (tid & 3) * 8;

  f32x4 acc[4][4] = {};

  for (int k0 = 0; k0 < D; k0 += 32) {
    __syncthreads();
    gl_lds16(Xs + (size_t)(bm + r0) * D + k0 + kg,      As + wave * 512 + lane * 8);
    gl_lds16(Xs + (size_t)(bm + 64 + r0) * D + k0 + kg, As + (4 + wave) * 512 + lane * 8);
    gl_lds16(Ws + (size_t)(bn + r0) * D + k0 + kg,      Bs + wave * 512 + lane * 8);
    gl_lds16(Ws + (size_t)(bn + 64 + r0) * D + k0 + kg, Bs + (4 + wave) * 512 + lane * 8);
    __syncthreads();
    bf16x8 af[4], bfr[4];
#pragma unroll
    for (int i = 0; i < 4; i++) {
      af[i]  = *(const bf16x8*)(As + (wm + i * 16 + q16) * 32 + quad * 8);
      bfr[i] = *(const bf16x8*)(Bs + (wn + i * 16 + q16) * 32 + quad * 8);
    }
#pragma unroll
    for (int mi = 0; mi < 4; mi++)
#pragma unroll
      for (int ni = 0; ni < 4; ni++)
        acc[mi][ni] = MFMA(af[mi], bfr[ni], acc[mi][ni]);
  }

  const float scl = (z == 0) ? 0.125f * 1.44269504f : 1.0f;
#pragma unroll
  for (int mi = 0; mi < 4; mi++) {
#pragma unroll
    for (int ni = 0; ni < 4; ni++) {
      const int gn = bn + wn + ni * 16 + q16;
      const float bb = load1(bias, gn, isf32);
      const int h = gn >> 6, hd = gn & 63;
      const int gm0 = bm + wm + mi * 16 + quad * 4;
      const int bidx = gm0 >> 11, s0 = gm0 & 2047;
      if (z == 2) {
        bf16x4 v4;
#pragma unroll
        for (int r = 0; r < 4; r++) v4[r] = (bf16)(acc[mi][ni][r] + bb);
        *(bf16x4*)(out + ((size_t)(bidx * H + h) * HD + hd) * S + s0) = v4;
      } else {
#pragma unroll
        for (int r = 0; r < 4; r++)
          out[((size_t)(bidx * H + h) * S + (s0 + r)) * HD + hd] = (bf16)((acc[mi][ni][r] + bb) * scl);
      }
    }
  }
}

// ---------------------------------------------------------------------------
// Flash attention v7: v6 structure (L2-resident K/V via XCD-grouped grid,
// FETCH 140MB->24.6MB) but occupancy-doubled. v6 post-mortem: dur only
// 147->137us because the kernel is TLP-starved, not memory-latency-bound:
// grid 512 = exactly 2 blocks/CU (Occupancy 21%), while 124 VGPR permits 4
// waves/SIMD. Fix: halve per-wave query work (2 q-sets = 32 queries/wave),
// grid 512 -> 1024 blocks, __launch_bounds__(256,4). Register arithmetic:
// v6 measured 124 with qf=32 + o=64 regs; halving both -> ~80-95 VGPR < 128
// cap, no spill. Per-XCD K/V working set unchanged (8 bh = 4MB = one L2).
// Q,K: [BH,S,HD]; Vt: [BH,HD,S]; mask: [B,S]; out: [B,S,D]
// ---------------------------------------------------------------------------
__global__ __launch_bounds__(256, 4) void attn(
    const bf16* __restrict__ Q, const bf16* __restrict__ K,
    const bf16* __restrict__ Vt, const void* __restrict__ mask,
    void* __restrict__ outv, const int* __restrict__ flagp) {
  const int fl = *flagp;
  const bool isf32 = (fl & 1) != 0;
  const bool havemask = (fl & 2) != 0;
  const int tid = threadIdx.x, lane = tid & 63, wave = tid >> 6;
  const int q16 = lane & 15, quad = lane >> 4;

  // XCD-grouped decomposition of the 1024-block 1-D grid (HW: XCD = bid % 8).
  const int bid = blockIdx.x;
  const int xcd = bid & 7, l = bid >> 3;       // l: 0..127
  const int bh = (xcd << 3) | (l & 7);         // XCD k handles bh 8k..8k+7
  const int qchunk = l >> 3;                   // 0..15
  const int b = bh >> 4, h = bh & 15;
  const int qbase = qchunk * 128 + wave * 32;  // wave covers 32 queries
  const float L2E = 1.44269504f;

  // Q B-frags: B[k=hd][n=q]: lane holds Q[q16][quad*8+j] per q-set, hd-chunk
  bf16x8 qf[2][2];
#pragma unroll
  for (int qs = 0; qs < 2; qs++) {
    const bf16* qr = Q + ((size_t)bh * S + qbase + qs * 16 + q16) * HD;
    qf[qs][0] = *(const bf16x8*)(qr + quad * 8);
    qf[qs][1] = *(const bf16x8*)(qr + 32 + quad * 8);
  }

  f32x4 o[2][4] = {};   // [qs][hi]  O^T accum: row=hd_local, col=query
  float racc[2] = {};   // per-lane rowsum (this lane's query q16, per q-set)

  const bf16* Kb = K + (size_t)bh * S * HD;
  const bf16* Vb = Vt + (size_t)bh * HD * S;
  const int kprow = 8 * (q16 >> 2) + (q16 & 3);  // lane's permuted-key row part
  const size_t mbase = (size_t)b * S;

  for (int t = 0; t < 32; t++) {
    const int kt = t * 64;
    // K A-frags, permuted key rows (contiguous 16 B loads)
    bf16x8 kf[4][2];
#pragma unroll
    for (int ki = 0; ki < 4; ki++) {
      const bf16* kr = Kb + (size_t)(kt + 32 * (ki >> 1) + 4 * (ki & 1) + kprow) * HD;
      kf[ki][0] = *(const bf16x8*)(kr + quad * 8);
      kf[ki][1] = *(const bf16x8*)(kr + 32 + quad * 8);
    }
    // V A-frags: Vt[16*hi+q16][kt + 32*hh + quad*8 ..+7]
    bf16x8 vf[4][2];
#pragma unroll
    for (int hi = 0; hi < 4; hi++) {
      const bf16* vr = Vb + (size_t)(hi * 16 + q16) * S + kt;
      vf[hi][0] = *(const bf16x8*)(vr + quad * 8);
      vf[hi][1] = *(const bf16x8*)(vr + 32 + quad * 8);
    }
    // mask at keys 32*(ki>>1)+4*(ki&1)+8*quad + r  (4 consecutive, aligned)
    f32x4 mk[4];
    if (havemask) {
#pragma unroll
      for (int ki = 0; ki < 4; ki++) {
        f32x4 mv = load4(mask, mbase + kt + 32 * (ki >> 1) + 4 * (ki & 1) + 8 * quad, isf32);
#pragma unroll
        for (int r = 0; r < 4; r++) mk[ki][r] = mv[r] * L2E;
      }
    }

#pragma unroll
    for (int qs = 0; qs < 2; qs++) {
      // Sc^T tiles: acc[ki][r] = Sc[q16][32*(ki>>1)+8*quad+4*(ki&1)+r]
      f32x4 sc[4];
      __builtin_amdgcn_s_setprio(1);
#pragma unroll
      for (int ki = 0; ki < 4; ki++) {
        f32x4 zz = {0.f, 0.f, 0.f, 0.f};
        zz = MFMA(kf[ki][0], qf[qs][0], zz);
        sc[ki] = MFMA(kf[ki][1], qf[qs][1], zz);
      }
      __builtin_amdgcn_s_setprio(0);
      // exp + in-lane pack into B-frags (natural key order) + tree rowsum
      bf16x8 pb[2];
      float rs = 0.f;
#pragma unroll
      for (int ki = 0; ki < 4; ki++) {
        const int hh = ki >> 1, half = (ki & 1) * 4;
        float p0, p1, p2, p3;
        if (havemask) {
          p0 = __builtin_amdgcn_exp2f(sc[ki][0] + mk[ki][0]);
          p1 = __builtin_amdgcn_exp2f(sc[ki][1] + mk[ki][1]);
          p2 = __builtin_amdgcn_exp2f(sc[ki][2] + mk[ki][2]);
          p3 = __builtin_amdgcn_exp2f(sc[ki][3] + mk[ki][3]);
        } else {
          p0 = __builtin_amdgcn_exp2f(sc[ki][0]);
          p1 = __builtin_amdgcn_exp2f(sc[ki][1]);
          p2 = __builtin_amdgcn_exp2f(sc[ki][2]);
          p3 = __builtin_amdgcn_exp2f(sc[ki][3]);
        }
        rs += ((p0 + p1) + (p2 + p3));
        pb[hh][half + 0] = (bf16)p0; pb[hh][half + 1] = (bf16)p1;
        pb[hh][half + 2] = (bf16)p2; pb[hh][half + 3] = (bf16)p3;
      }
      racc[qs] += rs;
      // O^T += Vt . P^T
      __builtin_amdgcn_s_setprio(1);
#pragma unroll
      for (int hi = 0; hi < 4; hi++) {
        o[qs][hi] = MFMA(vf[hi][0], pb[0], o[qs][hi]);
        o[qs][hi] = MFMA(vf[hi][1], pb[1], o[qs][hi]);
      }
      __builtin_amdgcn_s_setprio(0);
    }
  }

  // rowsum: reduce across the 4 quads holding the same query q16
#pragma unroll
  for (int qs = 0; qs < 2; qs++) {
    racc[qs] += __shfl_xor(racc[qs], 16);
    racc[qs] += __shfl_xor(racc[qs], 32);
  }

  // epilogue: out[b, qbase+qs*16+q16, h*64 + hi*16 + quad*4 + r] = o/racc
#pragma unroll
  for (int qs = 0; qs < 2; qs++) {
    const float inv = 1.0f / racc[qs];
    const size_t row = (size_t)b * S + qbase + qs * 16 + q16;
#pragma unroll
    for (int hi = 0; hi < 4; hi++) {
      const size_t off = row * D + h * HD + hi * 16 + quad * 4;
      if (isf32) {
        float4 st;
        st.x = o[qs][hi][0] * inv; st.y = o[qs][hi][1] * inv;
        st.z = o[qs][hi][2] * inv; st.w = o[qs][hi][3] * inv;
        *(float4*)((float*)outv + off) = st;
      } else {
        bf16x4 st;
#pragma unroll
        for (int r = 0; r < 4; r++) st[r] = (bf16)(o[qs][hi][r] * inv);
        *(bf16x4*)((bf16*)outv + off) = st;
      }
    }
  }
}

// ---------------------------------------------------------------------------
extern "C" void kernel_launch(void* const* d_in, const int* in_sizes, int n_in,
                              void* d_out, int out_size, void* d_ws, size_t ws_size,
                              hipStream_t stream) {
  const void* X    = d_in[0];
  const void* mask = d_in[1];
  const void* Wq = d_in[2]; const void* bq = d_in[3];
  const void* Wk = d_in[4]; const void* bk = d_in[5];
  const void* Wv = d_in[6]; const void* bv = d_in[7];

  const size_t elems = (size_t)M * D;  // 8 Mi
  bf16* Qw = (bf16*)d_ws;
  bf16* Kw = Qw + elems;
  bf16* Vw = Kw + elems;
  int* flag = (int*)(Vw + elems);

  // fp32 case: d_out (32 MB) stages bf16 X (16MB) + W (6MB).
  bf16* Xb = (bf16*)d_out;
  bf16* Wb = Xb + elems;

  hipMemsetAsync(flag, 0, sizeof(int), stream);
  detect_dtype<<<64, 256, 0, stream>>>((const uint4*)X, flag);
  detect_mask<<<8, 256, 0, stream>>>((const uint4*)mask, flag);
  convert_inputs<<<dim3(4096, 4), 256, 0, stream>>>(X, Wq, Wk, Wv, Xb, Wb, flag);
  qkv_gemm<<<dim3(M / 128, D / 128, 3), 256, 0, stream>>>(
      X, Xb, Wq, Wk, Wv, bq, bk, bv, Qw, Kw, Vw, Wb, flag);
  attn<<<dim3(1024), 256, 0, stream>>>(Qw, Kw, Vw, mask, d_out, flag);
}

// Round 4
// 311.814 us; speedup vs baseline: 1.8623x; 1.8623x over previous
//
#include <hip/hip_runtime.h>
#include <hip/hip_bf16.h>

typedef __bf16 bf16;
typedef __bf16 bf16x8 __attribute__((ext_vector_type(8)));
typedef __bf16 bf16x4 __attribute__((ext_vector_type(4)));
typedef float f32x4 __attribute__((ext_vector_type(4)));
typedef unsigned int u32;
typedef unsigned short u16;

constexpr int B_ = 4, S = 2048, D = 1024, H = 16, HD = 64;
constexpr int M = B_ * S;  // 8192

#define MFMA(a, b, c) __builtin_amdgcn_mfma_f32_16x16x32_bf16(a, b, c, 0, 0, 0)

// ---- async global->LDS, 16 B per lane (dest = wave-uniform base + lane*16) ----
__device__ inline void gl_lds16(const bf16* g, bf16* l) {
  __builtin_amdgcn_global_load_lds(
      (const __attribute__((address_space(1))) u32*)g,
      (__attribute__((address_space(3))) u32*)l, 16, 0, 0);
}

__device__ inline bf16x8 load8(const void* base, size_t idx, bool isf32) {
  if (isf32) {
    const float* p = (const float*)base + idx;
    const float4 a = *(const float4*)p;
    const float4 b = *(const float4*)(p + 4);
    bf16x8 r;
    r[0] = (bf16)a.x; r[1] = (bf16)a.y; r[2] = (bf16)a.z; r[3] = (bf16)a.w;
    r[4] = (bf16)b.x; r[5] = (bf16)b.y; r[6] = (bf16)b.z; r[7] = (bf16)b.w;
    return r;
  }
  return *(const bf16x8*)((const bf16*)base + idx);
}
__device__ inline float load1(const void* base, size_t idx, bool isf32) {
  return isf32 ? ((const float*)base)[idx] : (float)((const bf16*)base)[idx];
}
// 4 consecutive mask values (idx multiple of 4 -> aligned)
__device__ inline f32x4 load4(const void* base, size_t idx, bool isf32) {
  if (isf32) {
    const float4 v = *(const float4*)((const float*)base + idx);
    return {v.x, v.y, v.z, v.w};
  }
  const bf16x4 v = *(const bf16x4*)((const bf16*)base + idx);
  return {(float)v[0], (float)v[1], (float)v[2], (float)v[3]};
}

// swizzled LDS fragment read: physical byte = row*128 + (colbyte ^ ((row&7)<<4))
// (T2: spreads the 16 q16-rows of a frag read across 8 bank-groups -> 2-way max)
__device__ inline bf16x8 swzfrag(const bf16* buf, int row, int cb) {
  return *(const bf16x8*)((const char*)buf + row * 128 + (cb ^ ((row & 7) << 4)));
}

// ---------------------------------------------------------------------------
// flag bit0 = inputs are fp32; bit1 = mask has a nonzero element.
// flag is zeroed via hipMemsetAsync before these run.
// ---------------------------------------------------------------------------
__global__ __launch_bounds__(256) void detect_dtype(const uint4* __restrict__ X,
                                                    int* __restrict__ flag) {
  bool hit = false;
  for (int i = blockIdx.x * 256 + threadIdx.x; i < 32768; i += 64 * 256) {
    const uint4 v = X[i];
    const u32 w[4] = {v.x, v.y, v.z, v.w};
#pragma unroll
    for (int j = 0; j < 4; j++) {
      if (((w[j] >> 7) & 0xFFu) == 0xFFu) hit = true;
      if (((w[j] >> 23) & 0xFFu) == 0xFFu) hit = true;
    }
  }
  __shared__ int s;
  if (threadIdx.x == 0) s = 0;
  __syncthreads();
  if (hit) atomicOr(&s, 1);
  __syncthreads();
  if (threadIdx.x == 0 && s) atomicOr(flag, 1);
}

// runs after detect_dtype (stream-ordered): reads bit0 to size the mask scan.
__global__ __launch_bounds__(256) void detect_mask(const uint4* __restrict__ Mk,
                                                   int* __restrict__ flag) {
  const bool isf32 = (*flag & 1) != 0;
  const int n4 = (B_ * S * (isf32 ? 4 : 2)) / 16;  // 2048 (f32) or 1024 (bf16)
  bool nz = false;
  for (int i = blockIdx.x * 256 + threadIdx.x; i < n4; i += 8 * 256) {
    const uint4 v = Mk[i];
    nz |= ((v.x | v.y | v.z | v.w) != 0u);
  }
  __shared__ int s;
  if (threadIdx.x == 0) s = 0;
  __syncthreads();
  if (nz) atomicOr(&s, 1);
  __syncthreads();
  if (threadIdx.x == 0 && s) atomicOr(flag, 2);
}

// ---------------------------------------------------------------------------
// fp32 only: convert X -> Xb (d_out[0,16MB)), W q/k/v -> Wb (d_out+16MB).
// ---------------------------------------------------------------------------
__global__ __launch_bounds__(256) void convert_inputs(
    const void* __restrict__ X, const void* __restrict__ W0,
    const void* __restrict__ W1, const void* __restrict__ W2,
    bf16* __restrict__ Xb, bf16* __restrict__ Wb,
    const int* __restrict__ flagp) {
  if ((*flagp & 1) == 0) return;
  const int seg = blockIdx.y;
  const size_t n = (seg == 0) ? (size_t)M * D : (size_t)D * D;
  const size_t i0 = ((size_t)blockIdx.x * 256 + threadIdx.x) * 8;
  if (i0 >= n) return;
  const void* src = seg == 0 ? X : seg == 1 ? W0 : seg == 2 ? W1 : W2;
  bf16* dst = seg == 0 ? Xb : Wb + (size_t)(seg - 1) * D * D;
  *(bf16x8*)(dst + i0) = load8(src, i0, true);
}

// ---------------------------------------------------------------------------
// QKV GEMM v2: 256x256 tile, BK=64, 8 waves (2Mx4N), double-buffered 128KB
// LDS, depth-2 counted-vmcnt pipeline (T3+T4), XOR bank swizzle (T2),
// setprio around MFMA clusters (T5). grid (M/256, D/256, 3).
//   Pipeline: during K-tile kt (reading buf[kt&1]) we stage kt+2 into the
//   SAME buffer after all reads complete (lgkmcnt(0)+barrier), then
//   s_waitcnt vmcnt(8) -> waits only for kt+1's 8 loads; kt+2's 8 stay in
//   flight across the barrier. Loads never drain in steady state.
//   Swizzle (rule #21 both-sides): global_load_lds dest is linear; the
//   global SOURCE column is pre-inverse-swizzled, reads use swzfrag.
// z==0: Q*(0.125*log2e) [B,H,S,HD]; z==1: K; z==2: Vt [B,H,HD,S].
// ---------------------------------------------------------------------------
__global__ __launch_bounds__(512, 2) void qkv_gemm(
    const void* __restrict__ X0, const bf16* __restrict__ Xb,
    const void* __restrict__ W0, const void* __restrict__ W1, const void* __restrict__ W2,
    const void* __restrict__ b0, const void* __restrict__ b1, const void* __restrict__ b2,
    bf16* __restrict__ Qo, bf16* __restrict__ Ko, bf16* __restrict__ Vo,
    const bf16* __restrict__ Wb, const int* __restrict__ flagp) {
  const int z = blockIdx.z;
  const bool isf32 = (*flagp & 1) != 0;
  const void* Worig = z == 0 ? W0 : z == 1 ? W1 : W2;
  const void* bias  = z == 0 ? b0 : z == 1 ? b1 : b2;
  bf16* out         = z == 0 ? Qo : z == 1 ? Ko : Vo;
  const bf16* Xs = isf32 ? Xb : (const bf16*)X0;
  const bf16* Ws = isf32 ? (Wb + (size_t)z * D * D) : (const bf16*)Worig;

  __shared__ __align__(16) bf16 Asm[2][16384];  // 2 x 256rows x 64cols = 64KB
  __shared__ __align__(16) bf16 Bsm[2][16384];  // 64KB

  const int tid = threadIdx.x, lane = tid & 63;
  const int q16 = lane & 15, quad = lane >> 4;
  const int wid = tid >> 6, wr = wid >> 2, wc = wid & 3;  // 2 x 4 wave grid
  const int bm = blockIdx.x * 256, bn = blockIdx.y * 256;

  // staging geometry: thread stages 16B at linear LDS byte j*8192 + tid*16
  //   -> row = j*64 + (tid>>3), physcol = (tid&7)*16
  //   global source col pre-inverse-swizzled so swzfrag reads are correct.
  const int srow = tid >> 3;                                  // 0..63
  const int cel = ((((tid & 7) * 16) ^ ((srow & 7) << 4)) >> 1);  // elements
  int aOff[4], bOff[4];
#pragma unroll
  for (int j = 0; j < 4; j++) {
    aOff[j] = (bm + j * 64 + srow) * D + cel;
    bOff[j] = (bn + j * 64 + srow) * D + cel;
  }

  f32x4 acc[8][4] = {};

#define STAGE(sel, ktile)                                                     \
  {                                                                           \
    const int ko = (ktile) * 64;                                              \
    _Pragma("unroll") for (int j = 0; j < 4; j++)                             \
        gl_lds16(Xs + (size_t)(aOff[j] + ko), &Asm[sel][j * 4096 + tid * 8]); \
    _Pragma("unroll") for (int j = 0; j < 4; j++)                             \
        gl_lds16(Ws + (size_t)(bOff[j] + ko), &Bsm[sel][j * 4096 + tid * 8]); \
  }

  STAGE(0, 0);
  STAGE(1, 1);
  asm volatile("s_waitcnt vmcnt(8)" ::: "memory");  // tile0's 8 landed
  __builtin_amdgcn_s_barrier();

  const int NT = D / 64;  // 16
  for (int kt = 0; kt < NT; ++kt) {
    const bf16* Ab = Asm[kt & 1];
    const bf16* Bb = Bsm[kt & 1];
    bf16x8 a[8], u, v;
    // ---- phase 1: k-step 0, n-frags 0,1 ----
#pragma unroll
    for (int mf = 0; mf < 8; mf++) a[mf] = swzfrag(Ab, wr * 128 + mf * 16 + q16, quad * 16);
    u = swzfrag(Bb, wc * 64 + q16, quad * 16);
    v = swzfrag(Bb, wc * 64 + 16 + q16, quad * 16);
    __builtin_amdgcn_s_barrier();
    __builtin_amdgcn_s_setprio(1);
#pragma unroll
    for (int mf = 0; mf < 8; mf++) {
      acc[mf][0] = MFMA(a[mf], u, acc[mf][0]);
      acc[mf][1] = MFMA(a[mf], v, acc[mf][1]);
    }
    __builtin_amdgcn_s_setprio(0);
    __builtin_amdgcn_s_barrier();
    // ---- phase 2: k-step 0, n-frags 2,3 ----
    u = swzfrag(Bb, wc * 64 + 32 + q16, quad * 16);
    v = swzfrag(Bb, wc * 64 + 48 + q16, quad * 16);
    __builtin_amdgcn_s_barrier();
    __builtin_amdgcn_s_setprio(1);
#pragma unroll
    for (int mf = 0; mf < 8; mf++) {
      acc[mf][2] = MFMA(a[mf], u, acc[mf][2]);
      acc[mf][3] = MFMA(a[mf], v, acc[mf][3]);
    }
    __builtin_amdgcn_s_setprio(0);
    __builtin_amdgcn_s_barrier();
    // ---- phase 3: k-step 1, n-frags 0,1 ----
#pragma unroll
    for (int mf = 0; mf < 8; mf++) a[mf] = swzfrag(Ab, wr * 128 + mf * 16 + q16, 64 + quad * 16);
    u = swzfrag(Bb, wc * 64 + q16, 64 + quad * 16);
    v = swzfrag(Bb, wc * 64 + 16 + q16, 64 + quad * 16);
    __builtin_amdgcn_s_barrier();
    __builtin_amdgcn_s_setprio(1);
#pragma unroll
    for (int mf = 0; mf < 8; mf++) {
      acc[mf][0] = MFMA(a[mf], u, acc[mf][0]);
      acc[mf][1] = MFMA(a[mf], v, acc[mf][1]);
    }
    __builtin_amdgcn_s_setprio(0);
    __builtin_amdgcn_s_barrier();
    // ---- phase 4: k-step 1, n-frags 2,3; then stage kt+2 into cur ----
    u = swzfrag(Bb, wc * 64 + 32 + q16, 64 + quad * 16);
    v = swzfrag(Bb, wc * 64 + 48 + q16, 64 + quad * 16);
    __builtin_amdgcn_s_barrier();
    __builtin_amdgcn_s_setprio(1);
#pragma unroll
    for (int mf = 0; mf < 8; mf++) {
      acc[mf][2] = MFMA(a[mf], u, acc[mf][2]);
      acc[mf][3] = MFMA(a[mf], v, acc[mf][3]);
    }
    __builtin_amdgcn_s_setprio(0);
    // all waves' DS queues drained, then barrier: no in-flight read of cur
    // can observe the stage-writes issued below.
    asm volatile("s_waitcnt lgkmcnt(0)" ::: "memory");
    __builtin_amdgcn_s_barrier();  // BAR(1): safe to overwrite cur
    if (kt + 2 < NT) {
      STAGE(kt & 1, kt + 2);
      // outstanding: 8 (kt+1) + 8 (kt+2); wait only the oldest 8 (kt+1).
      asm volatile("s_waitcnt vmcnt(8)" ::: "memory");
    } else if (kt + 1 < NT) {
      asm volatile("s_waitcnt vmcnt(0)" ::: "memory");  // drain last tile
    }
    __builtin_amdgcn_s_barrier();  // BAR(2): next buffer ready
  }
#undef STAGE

  // epilogue (same output layouts as before; m = quad*4+r, n = q16)
  const float scl = (z == 0) ? 0.125f * 1.44269504f : 1.0f;
#pragma unroll
  for (int mf = 0; mf < 8; mf++) {
#pragma unroll
    for (int nf = 0; nf < 4; nf++) {
      const int gn = bn + wc * 64 + nf * 16 + q16;
      const float bb = load1(bias, gn, isf32);
      const int h = gn >> 6, hd = gn & 63;
      const int gm0 = bm + wr * 128 + mf * 16 + quad * 4;
      const int bidx = gm0 >> 11, s0 = gm0 & 2047;
      if (z == 2) {
        bf16x4 v4;
#pragma unroll
        for (int r = 0; r < 4; r++) v4[r] = (bf16)(acc[mf][nf][r] + bb);
        *(bf16x4*)(out + ((size_t)(bidx * H + h) * HD + hd) * S + s0) = v4;
      } else {
#pragma unroll
        for (int r = 0; r < 4; r++)
          out[((size_t)(bidx * H + h) * S + (s0 + r)) * HD + hd] =
              (bf16)((acc[mf][nf][r] + bb) * scl);
      }
    }
  }
}

// ---------------------------------------------------------------------------
// Flash attention v6 (round-2 winner, verbatim): ZERO LDS, zero barriers,
// wave = 64 queries (4 q-sets), XCD-grouped grid (per-XCD K/V = 4MB = one L2),
// mask-zero fast path, setprio, tree rowsum. 124 VGPR, 2 blocks/CU.
// Round-3 lesson: per-tile K/V frags (64 VGPR) are q-set-independent ->
// this structure cannot reach 4 waves/SIMD without LDS-sharing K/V.
// Q,K: [BH,S,HD]; Vt: [BH,HD,S]; mask: [B,S]; out: [B,S,D]
// ---------------------------------------------------------------------------
__global__ __launch_bounds__(256, 2) void attn(
    const bf16* __restrict__ Q, const bf16* __restrict__ K,
    const bf16* __restrict__ Vt, const void* __restrict__ mask,
    void* __restrict__ outv, const int* __restrict__ flagp) {
  const int fl = *flagp;
  const bool isf32 = (fl & 1) != 0;
  const bool havemask = (fl & 2) != 0;
  const int tid = threadIdx.x, lane = tid & 63, wave = tid >> 6;
  const int q16 = lane & 15, quad = lane >> 4;

  // XCD-grouped decomposition of the 512-block 1-D grid (HW: XCD = bid % 8).
  const int bid = blockIdx.x;
  const int xcd = bid & 7, l = bid >> 3;
  const int bh = (xcd << 3) | (l & 7);   // XCD k handles bh 8k..8k+7
  const int qchunk = l >> 3;             // 0..7
  const int b = bh >> 4, h = bh & 15;
  const int qbase = qchunk * 256 + wave * 64;
  const float L2E = 1.44269504f;

  // Q B-frags: B[k=hd][n=q]: lane holds Q[q16][quad*8+j] per q-set, hd-chunk
  bf16x8 qf[4][2];
#pragma unroll
  for (int qs = 0; qs < 4; qs++) {
    const bf16* qr = Q + ((size_t)bh * S + qbase + qs * 16 + q16) * HD;
    qf[qs][0] = *(const bf16x8*)(qr + quad * 8);
    qf[qs][1] = *(const bf16x8*)(qr + 32 + quad * 8);
  }

  f32x4 o[4][4] = {};   // [qs][hi]  O^T accum: row=hd_local, col=query
  float racc[4] = {};   // per-lane rowsum (this lane's query q16, per q-set)

  const bf16* Kb = K + (size_t)bh * S * HD;
  const bf16* Vb = Vt + (size_t)bh * HD * S;
  const int kprow = 8 * (q16 >> 2) + (q16 & 3);  // lane's permuted-key row part
  const size_t mbase = (size_t)b * S;

  for (int t = 0; t < 32; t++) {
    const int kt = t * 64;
    // K A-frags, permuted key rows (contiguous 16 B loads)
    bf16x8 kf[4][2];
#pragma unroll
    for (int ki = 0; ki < 4; ki++) {
      const bf16* kr = Kb + (size_t)(kt + 32 * (ki >> 1) + 4 * (ki & 1) + kprow) * HD;
      kf[ki][0] = *(const bf16x8*)(kr + quad * 8);
      kf[ki][1] = *(const bf16x8*)(kr + 32 + quad * 8);
    }
    // V A-frags: Vt[16*hi+q16][kt + 32*hh + quad*8 ..+7]
    bf16x8 vf[4][2];
#pragma unroll
    for (int hi = 0; hi < 4; hi++) {
      const bf16* vr = Vb + (size_t)(hi * 16 + q16) * S + kt;
      vf[hi][0] = *(const bf16x8*)(vr + quad * 8);
      vf[hi][1] = *(const bf16x8*)(vr + 32 + quad * 8);
    }
    // mask at keys 32*(ki>>1)+4*(ki&1)+8*quad + r  (4 consecutive, aligned)
    f32x4 mk[4];
    if (havemask) {
#pragma unroll
      for (int ki = 0; ki < 4; ki++) {
        f32x4 mv = load4(mask, mbase + kt + 32 * (ki >> 1) + 4 * (ki & 1) + 8 * quad, isf32);
#pragma unroll
        for (int r = 0; r < 4; r++) mk[ki][r] = mv[r] * L2E;
      }
    }

#pragma unroll
    for (int qs = 0; qs < 4; qs++) {
      // Sc^T tiles: acc[ki][r] = Sc[q16][32*(ki>>1)+8*quad+4*(ki&1)+r]
      f32x4 sc[4];
      __builtin_amdgcn_s_setprio(1);
#pragma unroll
      for (int ki = 0; ki < 4; ki++) {
        f32x4 zz = {0.f, 0.f, 0.f, 0.f};
        zz = MFMA(kf[ki][0], qf[qs][0], zz);
        sc[ki] = MFMA(kf[ki][1], qf[qs][1], zz);
      }
      __builtin_amdgcn_s_setprio(0);
      // exp + in-lane pack into B-frags (natural key order) + tree rowsum
      bf16x8 pb[2];
      float rs = 0.f;
#pragma unroll
      for (int ki = 0; ki < 4; ki++) {
        const int hh = ki >> 1, half = (ki & 1) * 4;
        float p0, p1, p2, p3;
        if (havemask) {
          p0 = __builtin_amdgcn_exp2f(sc[ki][0] + mk[ki][0]);
          p1 = __builtin_amdgcn_exp2f(sc[ki][1] + mk[ki][1]);
          p2 = __builtin_amdgcn_exp2f(sc[ki][2] + mk[ki][2]);
          p3 = __builtin_amdgcn_exp2f(sc[ki][3] + mk[ki][3]);
        } else {
          p0 = __builtin_amdgcn_exp2f(sc[ki][0]);
          p1 = __builtin_amdgcn_exp2f(sc[ki][1]);
          p2 = __builtin_amdgcn_exp2f(sc[ki][2]);
          p3 = __builtin_amdgcn_exp2f(sc[ki][3]);
        }
        rs += ((p0 + p1) + (p2 + p3));
        pb[hh][half + 0] = (bf16)p0; pb[hh][half + 1] = (bf16)p1;
        pb[hh][half + 2] = (bf16)p2; pb[hh][half + 3] = (bf16)p3;
      }
      racc[qs] += rs;
      // O^T += Vt . P^T
      __builtin_amdgcn_s_setprio(1);
#pragma unroll
      for (int hi = 0; hi < 4; hi++) {
        o[qs][hi] = MFMA(vf[hi][0], pb[0], o[qs][hi]);
        o[qs][hi] = MFMA(vf[hi][1], pb[1], o[qs][hi]);
      }
      __builtin_amdgcn_s_setprio(0);
    }
  }

  // rowsum: reduce across the 4 quads holding the same query q16
#pragma unroll
  for (int qs = 0; qs < 4; qs++) {
    racc[qs] += __shfl_xor(racc[qs], 16);
    racc[qs] += __shfl_xor(racc[qs], 32);
  }

  // epilogue: out[b, qbase+qs*16+q16, h*64 + hi*16 + quad*4 + r] = o/racc
#pragma unroll
  for (int qs = 0; qs < 4; qs++) {
    const float inv = 1.0f / racc[qs];
    const size_t row = (size_t)b * S + qbase + qs * 16 + q16;
#pragma unroll
    for (int hi = 0; hi < 4; hi++) {
      const size_t off = row * D + h * HD + hi * 16 + quad * 4;
      if (isf32) {
        float4 st;
        st.x = o[qs][hi][0] * inv; st.y = o[qs][hi][1] * inv;
        st.z = o[qs][hi][2] * inv; st.w = o[qs][hi][3] * inv;
        *(float4*)((float*)outv + off) = st;
      } else {
        bf16x4 st;
#pragma unroll
        for (int r = 0; r < 4; r++) st[r] = (bf16)(o[qs][hi][r] * inv);
        *(bf16x4*)((bf16*)outv + off) = st;
      }
    }
  }
}

// ---------------------------------------------------------------------------
extern "C" void kernel_launch(void* const* d_in, const int* in_sizes, int n_in,
                              void* d_out, int out_size, void* d_ws, size_t ws_size,
                              hipStream_t stream) {
  const void* X    = d_in[0];
  const void* mask = d_in[1];
  const void* Wq = d_in[2]; const void* bq = d_in[3];
  const void* Wk = d_in[4]; const void* bk = d_in[5];
  const void* Wv = d_in[6]; const void* bv = d_in[7];

  const size_t elems = (size_t)M * D;  // 8 Mi
  bf16* Qw = (bf16*)d_ws;
  bf16* Kw = Qw + elems;
  bf16* Vw = Kw + elems;
  int* flag = (int*)(Vw + elems);

  // fp32 case: d_out (32 MB) stages bf16 X (16MB) + W (6MB).
  bf16* Xb = (bf16*)d_out;
  bf16* Wb = Xb + elems;

  hipMemsetAsync(flag, 0, sizeof(int), stream);
  detect_dtype<<<64, 256, 0, stream>>>((const uint4*)X, flag);
  detect_mask<<<8, 256, 0, stream>>>((const uint4*)mask, flag);
  convert_inputs<<<dim3(4096, 4), 256, 0, stream>>>(X, Wq, Wk, Wv, Xb, Wb, flag);
  qkv_gemm<<<dim3(M / 256, D / 256, 3), 512, 0, stream>>>(
      X, Xb, Wq, Wk, Wv, bq, bk, bv, Qw, Kw, Vw, Wb, flag);
  attn<<<dim3(512), 256, 0, stream>>>(Qw, Kw, Vw, mask, d_out, flag);
}